// Round 2
// baseline (485.185 us; speedup 1.0000x reference)
//
#include <hip/hip_runtime.h>
#include <math.h>

#define PI_F      3.141592653f
#define TWO_PI_F  6.283185306f
#define HALF_PI_F 1.5707963265f
#define IOU_THR_F 0.1f

#define ST_UNKNOWN 0
#define ST_SEED    1
#define ST_NONSEED 2

__device__ __forceinline__ float limit_period_f(float v) {
    return v - floorf(v / TWO_PI_F + 0.5f) * TWO_PI_F;
}

// ---------------- Kernel 1: per-box prep (lo/hi/vol/dir) ----------------
__global__ void prep_kernel(const float* __restrict__ boxes, int n,
                            float* __restrict__ lox, float* __restrict__ loy, float* __restrict__ loz,
                            float* __restrict__ hix, float* __restrict__ hiy, float* __restrict__ hiz,
                            float* __restrict__ vol, float* __restrict__ dir) {
    int j = blockIdx.x * blockDim.x + threadIdx.x;
    if (j >= n) return;
    float b0 = boxes[j*7+0], b1 = boxes[j*7+1], b2 = boxes[j*7+2];
    float b3 = boxes[j*7+3], b4 = boxes[j*7+4], b5 = boxes[j*7+5];
    float b6 = boxes[j*7+6];
    // reference: c = boxes[:, :3]; d = boxes[:, [5,4,3]] = (l, w, h)
    lox[j] = b0 - b5*0.5f; hix[j] = b0 + b5*0.5f;
    loy[j] = b1 - b4*0.5f; hiy[j] = b1 + b4*0.5f;
    loz[j] = b2 - b3*0.5f; hiz[j] = b2 + b3*0.5f;
    vol[j] = (b5*b4)*b3;                   // d.prod(-1) order: l*w*h
    dir[j] = limit_period_f(b6);
}

// ---------------- Kernel 2: adjacency bit-matrix (iou > 0.1) ----------------
__global__ void adj_kernel(const float* __restrict__ lox, const float* __restrict__ loy,
                           const float* __restrict__ loz, const float* __restrict__ hix,
                           const float* __restrict__ hiy, const float* __restrict__ hiz,
                           const float* __restrict__ vol,
                           unsigned long long* __restrict__ adj, int n, int words) {
    int i = blockIdx.x;
    float lxi = lox[i], lyi = loy[i], lzi = loz[i];
    float hxi = hix[i], hyi = hiy[i], hzi = hiz[i];
    float vi  = vol[i];
    int tid = threadIdx.x;              // 256 threads = 4 waves
    int ntile = (n + 255) >> 8;
    for (int t = 0; t < ntile; ++t) {
        int j = (t << 8) + tid;
        bool pred = false;
        if (j < n) {
            float ix = fminf(hxi, hix[j]) - fmaxf(lxi, lox[j]); ix = fmaxf(ix, 0.0f);
            float iy = fminf(hyi, hiy[j]) - fmaxf(lyi, loy[j]); iy = fmaxf(iy, 0.0f);
            float iz = fminf(hzi, hiz[j]) - fmaxf(lzi, loz[j]); iz = fmaxf(iz, 0.0f);
            float inter = (ix*iy)*iz;
            float u = fmaxf(vi + vol[j] - inter, 1e-8f);
            pred = (inter / u) > IOU_THR_F;
        }
        unsigned long long m = __ballot(pred);
        if ((tid & 63) == 0) {
            int wi = j >> 6;
            if (wi < words) adj[(size_t)i * words + wi] = m;
        }
    }
}

// ---------------- Kernel 3: parallel greedy-seed fixpoint (single block) ----------------
// seed(i) <=> no earlier neighbor of i is a seed. Monotone fixpoint, Jacobi iteration.
__global__ void cluster_fix_kernel(const unsigned long long* __restrict__ adj,
                                   unsigned long long* __restrict__ seedMaskG,
                                   int* __restrict__ seedRankG,
                                   int* __restrict__ nclust,
                                   int n, int words) {
    __shared__ unsigned char status[4096];
    __shared__ int scanBuf[1024];
    __shared__ int changed;
    int tid = threadIdx.x;             // 1024
    int per = (n + 1023) >> 10;        // 4
    for (int k = tid; k < n; k += 1024) status[k] = ST_UNKNOWN;
    __syncthreads();
    for (;;) {
        if (tid == 0) changed = 0;
        __syncthreads();
        for (int k = 0; k < per; ++k) {
            int i = tid * per + k;
            if (i < n && status[i] == ST_UNKNOWN) {
                int wmax = i >> 6;
                bool sawSeed = false, allNon = true;
                for (int w = 0; w <= wmax && !sawSeed; ++w) {
                    unsigned long long m = adj[(size_t)i * words + w];
                    if (w == wmax) {
                        int sh = i & 63;
                        m = sh ? (m & ((1ull << sh) - 1ull)) : 0ull;
                    }
                    while (m) {
                        int b = __ffsll(m) - 1;
                        m &= m - 1;
                        unsigned char st = status[(w << 6) + b];
                        if (st == ST_SEED) { sawSeed = true; break; }
                        if (st == ST_UNKNOWN) allNon = false;
                    }
                }
                if (sawSeed)      { status[i] = ST_NONSEED; changed = 1; }
                else if (allNon)  { status[i] = ST_SEED;    changed = 1; }
            }
        }
        __syncthreads();
        if (!changed) break;
        __syncthreads();
    }
    // seed rank (inclusive cumsum of seed flags) = cid for each seed
    int base = tid * per;
    int f[8]; int cnt = 0;
    for (int k = 0; k < per && k < 8; ++k) {
        int i = base + k;
        int v = (i < n && status[i] == ST_SEED) ? 1 : 0;
        f[k] = v; cnt += v;
    }
    scanBuf[tid] = cnt;
    __syncthreads();
    for (int o = 1; o < 1024; o <<= 1) {
        int v = scanBuf[tid];
        int add = (tid >= o) ? scanBuf[tid - o] : 0;
        __syncthreads();
        scanBuf[tid] = v + add;
        __syncthreads();
    }
    int run = scanBuf[tid] - cnt;
    for (int k = 0; k < per && k < 8; ++k) {
        int i = base + k;
        if (i < n) { run += f[k]; seedRankG[i] = run; }
    }
    if (tid == 1023) *nclust = scanBuf[1023];
    // seed bitmask words
    if (tid < words) {
        unsigned long long m = 0ull;
        for (int b = 0; b < 64; ++b) {
            int j = (tid << 6) + b;
            if (j < n && status[j] == ST_SEED) m |= (1ull << b);
        }
        seedMaskG[tid] = m;
    }
}

// ---------------- Kernel 4: indices[j] = cid of max-index adjacent seed ----------------
__global__ void indices_kernel(const unsigned long long* __restrict__ adj,
                               const unsigned long long* __restrict__ seedMaskG,
                               const int* __restrict__ seedRankG,
                               int* __restrict__ indices, int n, int words) {
    __shared__ unsigned long long sm[64];
    int tid = threadIdx.x;  // 256
    if (tid < words) sm[tid] = seedMaskG[tid];
    __syncthreads();
    int j = blockIdx.x * blockDim.x + tid;
    if (j >= n) return;
    int best = -1;
    for (int w = words - 1; w >= 0; --w) {
        unsigned long long m = adj[(size_t)j * words + w] & sm[w];
        if (m) { best = (w << 6) + 63 - __clzll(m); break; }
    }
    indices[j] = (best >= 0) ? seedRankG[best] : 0;
}

// ---------------- Kernel 5: per-cluster fusion ----------------
__global__ void fusion_kernel(const float* __restrict__ boxes,
                              const float* __restrict__ scores,
                              const int* __restrict__ indices,
                              const float* __restrict__ dir,
                              const int* __restrict__ nclust,
                              float* __restrict__ fused,
                              float* __restrict__ sfused,
                              int* __restrict__ validArr, int n) {
    int i = blockIdx.x;           // output row; cluster id = i+1
    int tid = threadIdx.x;        // 256
    int cid = i + 1;
    if (cid > *nclust) {
        if (tid < 7) fused[i*7+tid] = 0.0f;
        if (tid == 0) { sfused[i] = 0.0f; validArr[i] = 0; }
        return;
    }
    __shared__ unsigned short js[4096];
    __shared__ float ms[4096];
    __shared__ int scanBuf[256];
    __shared__ int totalS;
    int chunk = (n + 255) >> 8;   // 16 for n=4096
    int start = tid * chunk;
    // pass 1: count
    int cnt = 0;
    for (int k = 0; k < chunk; ++k) {
        int j = start + k;
        if (j < n && indices[j] == cid) cnt++;
    }
    scanBuf[tid] = cnt;
    __syncthreads();
    for (int o = 1; o < 256; o <<= 1) {
        int v = scanBuf[tid];
        int add = (tid >= o) ? scanBuf[tid - o] : 0;
        __syncthreads();
        scanBuf[tid] = v + add;
        __syncthreads();
    }
    int excl = scanBuf[tid] - cnt;
    if (tid == 255) totalS = scanBuf[255];
    // pass 2: ordered write (deterministic, ascending j)
    int pos = excl;
    for (int k = 0; k < chunk; ++k) {
        int j = start + k;
        if (j < n && indices[j] == cid) js[pos++] = (unsigned short)j;
    }
    __syncthreads();
    int m = totalS;
    if (m == 0) {
        if (tid < 7) fused[i*7+tid] = 0.0f;
        if (tid == 0) { sfused[i] = 0.0f; validArr[i] = 0; }
        return;
    }
    for (int k = tid; k < m; k += 256) ms[k] = scores[js[k]];
    __syncthreads();
    if (tid == 0) {
        // s_sum and argmax (first occurrence of max; js ascending + strict >)
        float ssum = 0.0f, smax = -1e30f; int refj = js[0];
        for (int k = 0; k < m; ++k) {
            float s = ms[k];
            ssum += s;
            if (s > smax) { smax = s; refj = js[k]; }
        }
        float refdir = dir[refj];
        float denom = fmaxf(ssum, 1e-12f);
        // score_gt + weighted center/dim sums
        float sgt = 0.0f;
        float cd0=0,cd1=0,cd2=0,cd3=0,cd4=0,cd5=0;
        for (int k = 0; k < m; ++k) {
            int j = js[k];
            float s = ms[k];
            float d = fabsf(dir[j] - refdir);
            if (d > PI_F) d = TWO_PI_F - d;
            if (d > HALF_PI_F) sgt += s;
            float w = s / denom;
            cd0 += w * boxes[j*7+0];
            cd1 += w * boxes[j*7+1];
            cd2 += w * boxes[j*7+2];
            cd3 += w * boxes[j*7+3];
            cd4 += w * boxes[j*7+4];
            cd5 += w * boxes[j*7+5];
        }
        float sle = ssum - sgt;
        bool flipGt = (sgt <= sle);        // flip = flipGt ? gt : !gt
        float ssin = 0.0f, scos = 0.0f;
        for (int k = 0; k < m; ++k) {
            int j = js[k];
            float s = ms[k];
            float dj = dir[j];
            float d = fabsf(dj - refdir);
            if (d > PI_F) d = TWO_PI_F - d;
            bool gt = d > HALF_PI_F;
            bool flip = flipGt ? gt : !gt;
            float adj_d = limit_period_f(dj + (flip ? PI_F : 0.0f));
            float w = s / denom;
            ssin += sinf(adj_d) * w;
            scos += cosf(adj_d) * w;
        }
        float theta = atan2f(ssin, scos);
        // s_fused: sort member scores descending, sum s_k^(k+1)
        for (int k = 1; k < m; ++k) {
            float key = ms[k]; int p = k - 1;
            while (p >= 0 && ms[p] < key) { ms[p+1] = ms[p]; --p; }
            ms[p+1] = key;
        }
        float sf = 0.0f;
        for (int k = 0; k < m; ++k) sf += powf(ms[k], (float)(k+1));
        sf = fminf(sf, 1.0f);
        // corners range check (z never checked; 4 distinct xy corners)
        float c_ = cosf(theta), s_ = sinf(theta);
        float wdim = cd4, ldim = cd5;
        const float xs[4]  = {0.5f, 0.5f, -0.5f, -0.5f};
        const float ys_[4] = {-0.5f, 0.5f, 0.5f, -0.5f};
        bool inr = true;
        for (int c = 0; c < 4; ++c) {
            float cx = ldim * xs[c], cy = wdim * ys_[c];
            float rx = cx*c_ - cy*s_ + cd0;
            float ry = cx*s_ + cy*c_ + cd1;
            inr = inr && (rx > -140.8f) && (rx < 140.8f) && (ry > -40.0f) && (ry < 40.0f);
        }
        fused[i*7+0]=cd0; fused[i*7+1]=cd1; fused[i*7+2]=cd2;
        fused[i*7+3]=cd3; fused[i*7+4]=cd4; fused[i*7+5]=cd5;
        fused[i*7+6]=theta;
        sfused[i] = sf;
        validArr[i] = inr ? 1 : 0;
    }
}

// ---------------- Kernel 6: cumsum + gated output writes ----------------
__global__ void finalize_kernel(const float* __restrict__ fused,
                                const float* __restrict__ sfused,
                                const int* __restrict__ validArr,
                                const int* __restrict__ indices,
                                float* __restrict__ out, int n) {
    __shared__ int newidS[4096];
    __shared__ unsigned char validS[4096];
    __shared__ int scanBuf[1024];
    int tid = threadIdx.x;  // 1024
    int per = (n + 1023) >> 10;  // 4
    int base = tid * per;
    int v[8];
    int sum = 0;
    for (int k = 0; k < per && k < 8; ++k) {
        int j = base + k;
        int vv = (j < n) ? validArr[j] : 0;
        v[k] = vv; sum += vv;
    }
    scanBuf[tid] = sum;
    __syncthreads();
    for (int o = 1; o < 1024; o <<= 1) {
        int val = scanBuf[tid];
        int add = (tid >= o) ? scanBuf[tid - o] : 0;
        __syncthreads();
        scanBuf[tid] = val + add;
        __syncthreads();
    }
    int run = scanBuf[tid] - sum;
    for (int k = 0; k < per && k < 8; ++k) {
        int j = base + k;
        if (j < n) { run += v[k]; newidS[j] = run; validS[j] = (unsigned char)v[k]; }
    }
    __syncthreads();
    float* boxesO  = out;
    float* scoresO = out + (size_t)7*n;
    float* validO  = out + (size_t)8*n;
    float* idxO    = out + (size_t)9*n;
    for (int j = tid; j < n; j += 1024) {
        int vv = validS[j];
        #pragma unroll
        for (int k = 0; k < 7; ++k)
            boxesO[j*7+k] = vv ? fused[j*7+k] : 0.0f;
        scoresO[j] = vv ? sfused[j] : 0.0f;
        validO[j]  = vv ? 1.0f : 0.0f;
        int ind = indices[j];
        int safe = ind - 1; if (safe < 0) safe = 0;
        bool nv = (ind > 0) && (validS[safe] != 0);
        idxO[j] = nv ? (float)newidS[safe] : 0.0f;
    }
}

extern "C" void kernel_launch(void* const* d_in, const int* in_sizes, int n_in,
                              void* d_out, int out_size, void* d_ws, size_t ws_size,
                              hipStream_t stream) {
    const float* boxes  = (const float*)d_in[0];
    const float* scores = (const float*)d_in[1];
    int n = in_sizes[0] / 7;           // 4096
    int words = (n + 63) >> 6;         // 64

    char* ws = (char*)d_ws;
    size_t nf = (size_t)n * sizeof(float);
    size_t off = 0;
    float* lox = (float*)(ws + off); off += nf;
    float* loy = (float*)(ws + off); off += nf;
    float* loz = (float*)(ws + off); off += nf;
    float* hix = (float*)(ws + off); off += nf;
    float* hiy = (float*)(ws + off); off += nf;
    float* hiz = (float*)(ws + off); off += nf;
    float* vol = (float*)(ws + off); off += nf;
    float* dir = (float*)(ws + off); off += nf;
    off = (off + 7) & ~(size_t)7;
    unsigned long long* adj = (unsigned long long*)(ws + off);
    off += (size_t)n * words * sizeof(unsigned long long);
    unsigned long long* seedMask = (unsigned long long*)(ws + off);
    off += (size_t)words * sizeof(unsigned long long);
    int* seedRank = (int*)(ws + off); off += (size_t)n * sizeof(int);
    int* indices  = (int*)(ws + off); off += (size_t)n * sizeof(int);
    float* fused  = (float*)(ws + off); off += (size_t)n * 7 * sizeof(float);
    float* sfused = (float*)(ws + off); off += nf;
    int* validArr = (int*)(ws + off); off += (size_t)n * sizeof(int);
    int* nclust   = (int*)(ws + off); off += sizeof(int);

    prep_kernel<<<(n + 255) / 256, 256, 0, stream>>>(boxes, n, lox, loy, loz,
                                                     hix, hiy, hiz, vol, dir);
    adj_kernel<<<n, 256, 0, stream>>>(lox, loy, loz, hix, hiy, hiz, vol, adj, n, words);
    cluster_fix_kernel<<<1, 1024, 0, stream>>>(adj, seedMask, seedRank, nclust, n, words);
    indices_kernel<<<(n + 255) / 256, 256, 0, stream>>>(adj, seedMask, seedRank, indices, n, words);
    fusion_kernel<<<n, 256, 0, stream>>>(boxes, scores, indices, dir, nclust,
                                         fused, sfused, validArr, n);
    finalize_kernel<<<1, 1024, 0, stream>>>(fused, sfused, validArr, indices,
                                            (float*)d_out, n);
}

// Round 3
// 223.186 us; speedup vs baseline: 2.1739x; 2.1739x over previous
//
#include <hip/hip_runtime.h>
#include <math.h>

#define PI_F      3.141592653f
#define TWO_PI_F  6.283185306f
#define HALF_PI_F 1.5707963265f
#define IOU_THR_F 0.1f

typedef unsigned long long u64;

__device__ __forceinline__ float limit_period_f(float v) {
    return v - floorf(v / TWO_PI_F + 0.5f) * TWO_PI_F;
}

__device__ __forceinline__ u64 shfl_u64(u64 v, int src) {
    unsigned int lo = (unsigned int)(v & 0xffffffffull);
    unsigned int hi = (unsigned int)(v >> 32);
    lo = __shfl((int)lo, src);
    hi = __shfl((int)hi, src);
    return ((u64)hi << 32) | (u64)lo;
}

// ---------------- Kernel 1: per-box prep (lo/hi/vol/dir) ----------------
__global__ void prep_kernel(const float* __restrict__ boxes, int n,
                            float* __restrict__ lox, float* __restrict__ loy, float* __restrict__ loz,
                            float* __restrict__ hix, float* __restrict__ hiy, float* __restrict__ hiz,
                            float* __restrict__ vol, float* __restrict__ dir) {
    int j = blockIdx.x * blockDim.x + threadIdx.x;
    if (j >= n) return;
    float b0 = boxes[j*7+0], b1 = boxes[j*7+1], b2 = boxes[j*7+2];
    float b3 = boxes[j*7+3], b4 = boxes[j*7+4], b5 = boxes[j*7+5];
    float b6 = boxes[j*7+6];
    // reference: c = boxes[:, :3]; d = boxes[:, [5,4,3]] = (l, w, h)
    lox[j] = b0 - b5*0.5f; hix[j] = b0 + b5*0.5f;
    loy[j] = b1 - b4*0.5f; hiy[j] = b1 + b4*0.5f;
    loz[j] = b2 - b3*0.5f; hiz[j] = b2 + b3*0.5f;
    vol[j] = (b5*b4)*b3;                   // d.prod(-1) order: l*w*h
    dir[j] = limit_period_f(b6);
}

// ---------------- Kernel 2: adjacency bit-matrix, column-major-word layout ----
// adjC[(size_t)w * n + i] = word w of row i (bits for nodes 64w..64w+63)
__global__ void adj_kernel(const float* __restrict__ lox, const float* __restrict__ loy,
                           const float* __restrict__ loz, const float* __restrict__ hix,
                           const float* __restrict__ hiy, const float* __restrict__ hiz,
                           const float* __restrict__ vol,
                           u64* __restrict__ adjC, int n, int words) {
    int i = blockIdx.x;
    float lxi = lox[i], lyi = loy[i], lzi = loz[i];
    float hxi = hix[i], hyi = hiy[i], hzi = hiz[i];
    float vi  = vol[i];
    int tid = threadIdx.x;              // 256 threads = 4 waves
    int ntile = (n + 255) >> 8;
    for (int t = 0; t < ntile; ++t) {
        int j = (t << 8) + tid;
        bool pred = false;
        if (j < n) {
            float ix = fminf(hxi, hix[j]) - fmaxf(lxi, lox[j]); ix = fmaxf(ix, 0.0f);
            float iy = fminf(hyi, hiy[j]) - fmaxf(lyi, loy[j]); iy = fmaxf(iy, 0.0f);
            float iz = fminf(hzi, hiz[j]) - fmaxf(lzi, loz[j]); iz = fmaxf(iz, 0.0f);
            float inter = (ix*iy)*iz;
            float u = fmaxf(vi + vol[j] - inter, 1e-8f);
            pred = (inter / u) > IOU_THR_F;
        }
        u64 m = __ballot(pred);
        if ((tid & 63) == 0) {
            int wi = j >> 6;
            if (wi < words) adjC[(size_t)wi * n + i] = m;
        }
    }
}

// ---------------- Kernel 3: exact word-sequential greedy MIS (single block, 256 thr) --
// seed(i) <=> no earlier neighbor of i is a seed (lexicographically-first MIS).
__global__ void cluster_kernel(const u64* __restrict__ adjC,
                               u64* __restrict__ seedMaskG,
                               int* __restrict__ wordScanG,
                               int* __restrict__ nclust,
                               int n, int words) {
    __shared__ u64 eMaskS[64];     // bit i of word w: node 64w+i has earlier-word seed neighbor
    __shared__ u64 seedS[64];
    __shared__ int seedListS[64];
    __shared__ int cntS;
    int tid = threadIdx.x;         // 256
    if (tid < 64) { eMaskS[tid] = 0ull; seedS[tid] = 0ull; }
    __syncthreads();

    u64 A = 0ull;                  // lane's own diagonal-block adjacency word
    if (tid < 64 && tid < n) A = adjC[(size_t)0 * n + tid];

    for (int w = 0; w < words; ++w) {
        // prefetch next word's diagonal block (independent load, overlaps everything)
        u64 Anext = 0ull;
        if (w + 1 < words && tid < 64) {
            int node = ((w + 1) << 6) + tid;
            if (node < n) Anext = adjC[(size_t)(w + 1) * n + node];
        }
        if (tid < 64) {            // wave 0, all 64 lanes active
            int base = w << 6;
            int vb = n - base;
            u64 valid = (vb >= 64) ? ~0ull : ((vb <= 0) ? 0ull : ((1ull << vb) - 1ull));
            u64 notE  = ~eMaskS[w];
            u64 avail = valid;
            u64 s = 0ull;
            u64 cand = avail & notE;
            while (cand) {         // iterations = #seeds in this word (wave-uniform)
                int b = (int)__ffsll(cand) - 1;
                s |= 1ull << b;
                u64 Ab = shfl_u64(A, b);      // seed b's within-word adjacency
                avail &= ~Ab;
                u64 himask = (b >= 63) ? 0ull : ~((2ull << b) - 1ull);
                cand = avail & notE & himask;
            }
            seedS[w] = s;
            if ((s >> tid) & 1ull) {
                int pos = __popcll(s & ((1ull << tid) - 1ull));
                seedListS[pos] = base + tid;
            }
            if (tid == 0) cntS = __popcll(s);
        }
        __syncthreads();
        // eager eMask update: OR each new seed's adjacency into future words
        int cnt = cntS;
        int nu = words - 1 - w;
        int P = cnt * nu;
        for (int p = tid; p < P; p += 256) {
            int ci = p / nu;
            int wi = w + 1 + (p - ci * nu);
            u64 v = adjC[(size_t)wi * n + seedListS[ci]];   // row seed, word wi (symmetric layout)
            if (v) atomicOr(&eMaskS[wi], v);
        }
        __syncthreads();
        A = Anext;
    }
    if (tid < words) seedMaskG[tid] = seedS[tid];
    if (tid == 0) {
        int run = 0;
        for (int w2 = 0; w2 < words; ++w2) { wordScanG[w2] = run; run += __popcll(seedS[w2]); }
        *nclust = run;
    }
}

// ---------------- Kernel 4: indices[j] = cid of max-index adjacent seed ----------------
__global__ void indices_kernel(const u64* __restrict__ adjC,
                               const u64* __restrict__ seedMaskG,
                               const int* __restrict__ wordScanG,
                               int* __restrict__ indices, int n, int words) {
    __shared__ u64 sm[64];
    __shared__ int wsS[64];
    int tid = threadIdx.x;  // 256
    if (tid < words) { sm[tid] = seedMaskG[tid]; wsS[tid] = wordScanG[tid]; }
    __syncthreads();
    int j = blockIdx.x * blockDim.x + tid;
    if (j >= n) return;
    int idx = 0;
    for (int w = words - 1; w >= 0; --w) {
        u64 m = adjC[(size_t)w * n + j] & sm[w];   // coalesced across j
        if (m) {
            int b = 63 - (int)__clzll(m);
            u64 incl = (b >= 63) ? ~0ull : ((2ull << b) - 1ull);
            idx = wsS[w] + __popcll(sm[w] & incl);  // inclusive rank = 1-based cid
            break;
        }
    }
    indices[j] = idx;
}

// ---------------- Kernel 5: per-cluster fusion ----------------
__global__ void fusion_kernel(const float* __restrict__ boxes,
                              const float* __restrict__ scores,
                              const int* __restrict__ indices,
                              const float* __restrict__ dir,
                              const int* __restrict__ nclust,
                              float* __restrict__ fused,
                              float* __restrict__ sfused,
                              int* __restrict__ validArr, int n) {
    int i = blockIdx.x;           // output row; cluster id = i+1
    int tid = threadIdx.x;        // 256
    int cid = i + 1;
    if (cid > *nclust) {
        if (tid < 7) fused[i*7+tid] = 0.0f;
        if (tid == 0) { sfused[i] = 0.0f; validArr[i] = 0; }
        return;
    }
    __shared__ unsigned short js[4096];
    __shared__ float ms[4096];
    __shared__ int scanBuf[256];
    __shared__ int totalS;
    int chunk = (n + 255) >> 8;   // 16 for n=4096
    int start = tid * chunk;
    // pass 1: count
    int cnt = 0;
    for (int k = 0; k < chunk; ++k) {
        int j = start + k;
        if (j < n && indices[j] == cid) cnt++;
    }
    scanBuf[tid] = cnt;
    __syncthreads();
    for (int o = 1; o < 256; o <<= 1) {
        int v = scanBuf[tid];
        int add = (tid >= o) ? scanBuf[tid - o] : 0;
        __syncthreads();
        scanBuf[tid] = v + add;
        __syncthreads();
    }
    int excl = scanBuf[tid] - cnt;
    if (tid == 255) totalS = scanBuf[255];
    // pass 2: ordered write (deterministic, ascending j)
    int pos = excl;
    for (int k = 0; k < chunk; ++k) {
        int j = start + k;
        if (j < n && indices[j] == cid) js[pos++] = (unsigned short)j;
    }
    __syncthreads();
    int m = totalS;
    if (m == 0) {
        if (tid < 7) fused[i*7+tid] = 0.0f;
        if (tid == 0) { sfused[i] = 0.0f; validArr[i] = 0; }
        return;
    }
    for (int k = tid; k < m; k += 256) ms[k] = scores[js[k]];
    __syncthreads();
    if (tid == 0) {
        // s_sum and argmax (first occurrence of max; js ascending + strict >)
        float ssum = 0.0f, smax = -1e30f; int refj = js[0];
        for (int k = 0; k < m; ++k) {
            float s = ms[k];
            ssum += s;
            if (s > smax) { smax = s; refj = js[k]; }
        }
        float refdir = dir[refj];
        float denom = fmaxf(ssum, 1e-12f);
        // score_gt + weighted center/dim sums
        float sgt = 0.0f;
        float cd0=0,cd1=0,cd2=0,cd3=0,cd4=0,cd5=0;
        for (int k = 0; k < m; ++k) {
            int j = js[k];
            float s = ms[k];
            float d = fabsf(dir[j] - refdir);
            if (d > PI_F) d = TWO_PI_F - d;
            if (d > HALF_PI_F) sgt += s;
            float w = s / denom;
            cd0 += w * boxes[j*7+0];
            cd1 += w * boxes[j*7+1];
            cd2 += w * boxes[j*7+2];
            cd3 += w * boxes[j*7+3];
            cd4 += w * boxes[j*7+4];
            cd5 += w * boxes[j*7+5];
        }
        float sle = ssum - sgt;
        bool flipGt = (sgt <= sle);        // flip = flipGt ? gt : !gt
        float ssin = 0.0f, scos = 0.0f;
        for (int k = 0; k < m; ++k) {
            int j = js[k];
            float s = ms[k];
            float dj = dir[j];
            float d = fabsf(dj - refdir);
            if (d > PI_F) d = TWO_PI_F - d;
            bool gt = d > HALF_PI_F;
            bool flip = flipGt ? gt : !gt;
            float adj_d = limit_period_f(dj + (flip ? PI_F : 0.0f));
            float w = s / denom;
            ssin += sinf(adj_d) * w;
            scos += cosf(adj_d) * w;
        }
        float theta = atan2f(ssin, scos);
        // s_fused: sort member scores descending, sum s_k^(k+1)
        for (int k = 1; k < m; ++k) {
            float key = ms[k]; int p = k - 1;
            while (p >= 0 && ms[p] < key) { ms[p+1] = ms[p]; --p; }
            ms[p+1] = key;
        }
        float sf = 0.0f;
        for (int k = 0; k < m; ++k) sf += powf(ms[k], (float)(k+1));
        sf = fminf(sf, 1.0f);
        // corners range check (z never checked; 4 distinct xy corners)
        float c_ = cosf(theta), s_ = sinf(theta);
        float wdim = cd4, ldim = cd5;
        const float xs[4]  = {0.5f, 0.5f, -0.5f, -0.5f};
        const float ys_[4] = {-0.5f, 0.5f, 0.5f, -0.5f};
        bool inr = true;
        for (int c = 0; c < 4; ++c) {
            float cx = ldim * xs[c], cy = wdim * ys_[c];
            float rx = cx*c_ - cy*s_ + cd0;
            float ry = cx*s_ + cy*c_ + cd1;
            inr = inr && (rx > -140.8f) && (rx < 140.8f) && (ry > -40.0f) && (ry < 40.0f);
        }
        fused[i*7+0]=cd0; fused[i*7+1]=cd1; fused[i*7+2]=cd2;
        fused[i*7+3]=cd3; fused[i*7+4]=cd4; fused[i*7+5]=cd5;
        fused[i*7+6]=theta;
        sfused[i] = sf;
        validArr[i] = inr ? 1 : 0;
    }
}

// ---------------- Kernel 6: cumsum + gated output writes ----------------
__global__ void finalize_kernel(const float* __restrict__ fused,
                                const float* __restrict__ sfused,
                                const int* __restrict__ validArr,
                                const int* __restrict__ indices,
                                float* __restrict__ out, int n) {
    __shared__ int newidS[4096];
    __shared__ unsigned char validS[4096];
    __shared__ int scanBuf[1024];
    int tid = threadIdx.x;  // 1024
    int per = (n + 1023) >> 10;  // 4
    int base = tid * per;
    int v[8];
    int sum = 0;
    for (int k = 0; k < per && k < 8; ++k) {
        int j = base + k;
        int vv = (j < n) ? validArr[j] : 0;
        v[k] = vv; sum += vv;
    }
    scanBuf[tid] = sum;
    __syncthreads();
    for (int o = 1; o < 1024; o <<= 1) {
        int val = scanBuf[tid];
        int add = (tid >= o) ? scanBuf[tid - o] : 0;
        __syncthreads();
        scanBuf[tid] = val + add;
        __syncthreads();
    }
    int run = scanBuf[tid] - sum;
    for (int k = 0; k < per && k < 8; ++k) {
        int j = base + k;
        if (j < n) { run += v[k]; newidS[j] = run; validS[j] = (unsigned char)v[k]; }
    }
    __syncthreads();
    float* boxesO  = out;
    float* scoresO = out + (size_t)7*n;
    float* validO  = out + (size_t)8*n;
    float* idxO    = out + (size_t)9*n;
    for (int j = tid; j < n; j += 1024) {
        int vv = validS[j];
        #pragma unroll
        for (int k = 0; k < 7; ++k)
            boxesO[j*7+k] = vv ? fused[j*7+k] : 0.0f;
        scoresO[j] = vv ? sfused[j] : 0.0f;
        validO[j]  = vv ? 1.0f : 0.0f;
        int ind = indices[j];
        int safe = ind - 1; if (safe < 0) safe = 0;
        bool nv = (ind > 0) && (validS[safe] != 0);
        idxO[j] = nv ? (float)newidS[safe] : 0.0f;
    }
}

extern "C" void kernel_launch(void* const* d_in, const int* in_sizes, int n_in,
                              void* d_out, int out_size, void* d_ws, size_t ws_size,
                              hipStream_t stream) {
    const float* boxes  = (const float*)d_in[0];
    const float* scores = (const float*)d_in[1];
    int n = in_sizes[0] / 7;           // 4096
    int words = (n + 63) >> 6;         // 64

    char* ws = (char*)d_ws;
    size_t nf = (size_t)n * sizeof(float);
    size_t off = 0;
    float* lox = (float*)(ws + off); off += nf;
    float* loy = (float*)(ws + off); off += nf;
    float* loz = (float*)(ws + off); off += nf;
    float* hix = (float*)(ws + off); off += nf;
    float* hiy = (float*)(ws + off); off += nf;
    float* hiz = (float*)(ws + off); off += nf;
    float* vol = (float*)(ws + off); off += nf;
    float* dir = (float*)(ws + off); off += nf;
    off = (off + 7) & ~(size_t)7;
    u64* adjC = (u64*)(ws + off);
    off += (size_t)n * words * sizeof(u64);
    u64* seedMask = (u64*)(ws + off); off += (size_t)words * sizeof(u64);
    int* wordScan = (int*)(ws + off); off += (size_t)words * sizeof(int);
    int* indices  = (int*)(ws + off); off += (size_t)n * sizeof(int);
    float* fused  = (float*)(ws + off); off += (size_t)n * 7 * sizeof(float);
    float* sfused = (float*)(ws + off); off += nf;
    int* validArr = (int*)(ws + off); off += (size_t)n * sizeof(int);
    int* nclust   = (int*)(ws + off); off += sizeof(int);

    prep_kernel<<<(n + 255) / 256, 256, 0, stream>>>(boxes, n, lox, loy, loz,
                                                     hix, hiy, hiz, vol, dir);
    adj_kernel<<<n, 256, 0, stream>>>(lox, loy, loz, hix, hiy, hiz, vol, adjC, n, words);
    cluster_kernel<<<1, 256, 0, stream>>>(adjC, seedMask, wordScan, nclust, n, words);
    indices_kernel<<<(n + 255) / 256, 256, 0, stream>>>(adjC, seedMask, wordScan, indices, n, words);
    fusion_kernel<<<n, 256, 0, stream>>>(boxes, scores, indices, dir, nclust,
                                         fused, sfused, validArr, n);
    finalize_kernel<<<1, 1024, 0, stream>>>(fused, sfused, validArr, indices,
                                            (float*)d_out, n);
}